// Round 2
// baseline (4421.882 us; speedup 1.0000x reference)
//
#include <hip/hip_runtime.h>
#include <math.h>

#define N_NODES 50000
#define N_EDGES 800000
#define T_SEQ   16
#define F_NODE  8
#define D_TXT   64
#define HDIM    64

// ---------------------------------------------------------------- degree prep
__global__ void k_init_deg(float* __restrict__ deg) {
    int i = blockIdx.x * 256 + threadIdx.x;
    if (i < N_NODES) deg[i] = 1.0f;   // self loop
}

__global__ void k_deg(const int* __restrict__ ei, float* __restrict__ deg) {
    int e = blockIdx.x * 256 + threadIdx.x;
    if (e < N_EDGES) atomicAdd(&deg[ei[N_EDGES + e]], 1.0f);
}

__global__ void k_dinv(float* __restrict__ deg) {
    int i = blockIdx.x * 256 + threadIdx.x;
    if (i < N_NODES) deg[i] = rsqrtf(fmaxf(deg[i], 1.0f));   // in place -> dinv
}

// ---------------------------------------------------------------- GRU (fused embedding)
// one wave per node; weights transposed in LDS: w_t[k][g*64+j] = w[g*64+j][k]
__global__ __launch_bounds__(1024) void k_gru(
    const float* __restrict__ x,       // [N,8]
    const int*   __restrict__ xtext,   // [N,16]
    const float* __restrict__ embed,   // [VOCAB,64]
    const float* __restrict__ w_ih,    // [192,64]
    const float* __restrict__ w_hh,    // [192,64]
    const float* __restrict__ b_ih,    // [192]
    const float* __restrict__ b_hh,    // [192]
    float* __restrict__ hcat)          // [N,72]  = [x | h_T]
{
    __shared__ float wih_t[64 * 192];
    __shared__ float whh_t[64 * 192];
    const int tid = threadIdx.x;
    for (int i = tid; i < 192 * 64; i += 1024) {
        int r = i >> 6, k = i & 63;
        wih_t[k * 192 + r] = w_ih[i];
        whh_t[k * 192 + r] = w_hh[i];
    }
    __syncthreads();

    const int lane  = tid & 63;
    const int wave  = tid >> 6;
    const int gwave = blockIdx.x * 16 + wave;
    const int nwv   = gridDim.x * 16;

    const float bir = b_ih[lane], biz = b_ih[64 + lane], bin_ = b_ih[128 + lane];
    const float bhr = b_hh[lane], bhz = b_hh[64 + lane], bhn  = b_hh[128 + lane];

    for (int n = gwave; n < N_NODES; n += nwv) {
        float h = 0.0f;
        const int* xt = xtext + n * T_SEQ;
        for (int t = 0; t < T_SEQ; ++t) {
            int   idx = xt[t];                       // wave-uniform broadcast
            float e   = embed[idx * 64 + lane];
            float gir = bir, giz = biz, gin = bin_;
            float ghr = bhr, ghz = bhz, ghn = bhn;
            #pragma unroll 8
            for (int k = 0; k < 64; ++k) {
                float ek = __shfl(e, k, 64);
                float hk = __shfl(h, k, 64);
                const float* wi = &wih_t[k * 192 + lane];
                const float* wh = &whh_t[k * 192 + lane];
                gir += ek * wi[0];
                giz += ek * wi[64];
                gin += ek * wi[128];
                ghr += hk * wh[0];
                ghz += hk * wh[64];
                ghn += hk * wh[128];
            }
            float r  = 1.0f / (1.0f + __expf(-(gir + ghr)));
            float z  = 1.0f / (1.0f + __expf(-(giz + ghz)));
            float nn = tanhf(gin + r * ghn);
            h = (1.0f - z) * nn + z * h;
        }
        hcat[n * 72 + 8 + lane] = h;
        if (lane < F_NODE) hcat[n * 72 + lane] = x[n * F_NODE + lane];
    }
}

// ---------------------------------------------------------------- dense m = X @ W  (K in {72,64})
template <int K>
__global__ void k_mm(const float* __restrict__ X, const float* __restrict__ W,
                     float* __restrict__ M) {
    __shared__ float Wl[K * 64];
    int tid = threadIdx.x;   // 256
    for (int i = tid; i < K * 64; i += 256) Wl[i] = W[i];
    __syncthreads();
    int j = tid & 63;
    int n = blockIdx.x * 4 + (tid >> 6);
    if (n >= N_NODES) return;
    const float* xr = X + n * K;
    float acc = 0.0f;
    #pragma unroll
    for (int k = 0; k < K; ++k) acc += xr[k] * Wl[k * 64 + j];
    M[n * 64 + j] = acc;
}

// ---------------------------------------------------------------- scatter: acc[col] += dinv[r]*dinv[c]*m[row]
__global__ void k_scatter(const int* __restrict__ ei, const float* __restrict__ m,
                          const float* __restrict__ dinv, float* __restrict__ acc) {
    int e = blockIdx.x * 4 + (threadIdx.x >> 6);
    if (e >= N_EDGES) return;
    int j = threadIdx.x & 63;
    int r = ei[e], c = ei[N_EDGES + e];
    float nrm = dinv[r] * dinv[c];
    atomicAdd(&acc[c * 64 + j], nrm * m[r * 64 + j]);
}

// ---------------------------------------------------------------- combine: out = relu(acc + dinv^2*m + b)
__global__ void k_combine(const float* __restrict__ acc, const float* __restrict__ m,
                          const float* __restrict__ dinv, const float* __restrict__ b,
                          float* __restrict__ out) {
    int i = blockIdx.x * 256 + threadIdx.x;
    if (i >= N_NODES * 64) return;
    int n = i >> 6, j = i & 63;
    float d = dinv[n];
    float v = acc[i] + d * d * m[i] + b[j];
    out[i] = fmaxf(v, 0.0f);
}

// ---------------------------------------------------------------- edge classifier + log_softmax
__global__ __launch_bounds__(512) void k_edge(
    const int* __restrict__ ei, const float* __restrict__ h,   // h2 [N,64]
    const float* __restrict__ Wl1, const float* __restrict__ bl1,
    const float* __restrict__ Wf,  const float* __restrict__ bf,
    float* __restrict__ out)       // [E,2]
{
    __shared__ float Wl[128 * 64];
    int tid = threadIdx.x;
    for (int i = tid; i < 128 * 64; i += 512) Wl[i] = Wl1[i];
    __syncthreads();
    int lane = tid & 63;
    int e = blockIdx.x * 8 + (tid >> 6);
    if (e >= N_EDGES) return;
    int s = ei[e], d = ei[N_EDGES + e];
    float hs = h[s * 64 + lane];
    float hd = h[d * 64 + lane];
    float acc = bl1[lane];
    #pragma unroll 8
    for (int k = 0; k < 64; ++k) {
        float a  = __shfl(hs, k, 64);
        float b2 = __shfl(hd, k, 64);
        acc += a  * Wl[k * 64 + lane];
        acc += b2 * Wl[(64 + k) * 64 + lane];
    }
    float hid = fmaxf(acc, 0.0f);
    float p0 = hid * Wf[lane * 2 + 0];
    float p1 = hid * Wf[lane * 2 + 1];
    #pragma unroll
    for (int off = 32; off > 0; off >>= 1) {
        p0 += __shfl_xor(p0, off, 64);
        p1 += __shfl_xor(p1, off, 64);
    }
    if (lane == 0) {
        float l0 = p0 + bf[0], l1 = p1 + bf[1];
        float mx  = fmaxf(l0, l1);
        float lse = mx + logf(__expf(l0 - mx) + __expf(l1 - mx));
        out[e * 2 + 0] = l0 - lse;
        out[e * 2 + 1] = l1 - lse;
    }
}

// ---------------------------------------------------------------- launch
extern "C" void kernel_launch(void* const* d_in, const int* in_sizes, int n_in,
                              void* d_out, int out_size, void* d_ws, size_t ws_size,
                              hipStream_t stream) {
    const float* x     = (const float*)d_in[0];
    const int*   ei    = (const int*)  d_in[1];
    const int*   xtext = (const int*)  d_in[2];
    const float* embed = (const float*)d_in[3];
    const float* w_ih  = (const float*)d_in[4];
    const float* w_hh  = (const float*)d_in[5];
    const float* b_ih  = (const float*)d_in[6];
    const float* b_hh  = (const float*)d_in[7];
    const float* W1    = (const float*)d_in[8];
    const float* b1    = (const float*)d_in[9];
    const float* W2    = (const float*)d_in[10];
    const float* b2    = (const float*)d_in[11];
    const float* Wl1   = (const float*)d_in[12];
    const float* bl1   = (const float*)d_in[13];
    const float* Wf    = (const float*)d_in[14];
    const float* bf    = (const float*)d_in[15];
    float* out = (float*)d_out;

    char* ws = (char*)d_ws;
    size_t off = 0;
    auto alloc = [&](size_t bytes) { char* p = ws + off; off += (bytes + 255) & ~size_t(255); return p; };
    float* hcat = (float*)alloc(N_NODES * 72 * 4);
    float* mbuf = (float*)alloc(N_NODES * 64 * 4);
    float* accb = (float*)alloc(N_NODES * 64 * 4);
    float* h1   = (float*)alloc(N_NODES * 64 * 4);
    float* h2   = (float*)alloc(N_NODES * 64 * 4);
    float* dinv = (float*)alloc(N_NODES * 4);

    // degree / normalization
    k_init_deg<<<(N_NODES + 255) / 256, 256, 0, stream>>>(dinv);
    k_deg<<<(N_EDGES + 255) / 256, 256, 0, stream>>>(ei, dinv);
    k_dinv<<<(N_NODES + 255) / 256, 256, 0, stream>>>(dinv);

    // text encoder
    k_gru<<<256, 1024, 0, stream>>>(x, xtext, embed, w_ih, w_hh, b_ih, b_hh, hcat);

    // GCN layer 1
    k_mm<72><<<(N_NODES + 3) / 4, 256, 0, stream>>>(hcat, W1, mbuf);
    hipMemsetAsync(accb, 0, N_NODES * 64 * 4, stream);
    k_scatter<<<(N_EDGES + 3) / 4, 256, 0, stream>>>(ei, mbuf, dinv, accb);
    k_combine<<<(N_NODES * 64 + 255) / 256, 256, 0, stream>>>(accb, mbuf, dinv, b1, h1);

    // GCN layer 2
    k_mm<64><<<(N_NODES + 3) / 4, 256, 0, stream>>>(h1, W2, mbuf);
    hipMemsetAsync(accb, 0, N_NODES * 64 * 4, stream);
    k_scatter<<<(N_EDGES + 3) / 4, 256, 0, stream>>>(ei, mbuf, dinv, accb);
    k_combine<<<(N_NODES * 64 + 255) / 256, 256, 0, stream>>>(accb, mbuf, dinv, b2, h2);

    // edge classifier
    k_edge<<<(N_EDGES + 7) / 8, 512, 0, stream>>>(ei, h2, Wl1, bl1, Wf, bf, out);
}

// Round 3
// 711.403 us; speedup vs baseline: 6.2157x; 6.2157x over previous
//
#include <hip/hip_runtime.h>
#include <math.h>

#define N_NODES 50000
#define N_EDGES 800000

typedef __attribute__((ext_vector_type(8))) short bf16x8;
typedef __attribute__((ext_vector_type(4))) float f32x4;

__device__ inline short f2bf(float f) {
    union { float f; unsigned u; } v; v.f = f;
    unsigned r = v.u + 0x7FFFu + ((v.u >> 16) & 1u);   // RNE
    return (short)(r >> 16);
}

__device__ inline float fsig(float x)  { return __builtin_amdgcn_rcpf(1.0f + __expf(-x)); }
__device__ inline float ftanh(float x) { float t = __expf(2.0f * x); return 1.0f - 2.0f * __builtin_amdgcn_rcpf(t + 1.0f); }

__device__ inline f32x4 mfma16(bf16x8 a, bf16x8 b, f32x4 c) {
    return __builtin_amdgcn_mfma_f32_16x16x32_bf16(a, b, c, 0, 0, 0);
}

// ---------------------------------------------------------------- degree prep
__global__ void k_init_deg(float* __restrict__ deg) {
    int i = blockIdx.x * 256 + threadIdx.x;
    if (i < N_NODES) deg[i] = 1.0f;
}
__global__ void k_deg(const int* __restrict__ ei, float* __restrict__ deg) {
    int e = blockIdx.x * 256 + threadIdx.x;
    if (e < N_EDGES) atomicAdd(&deg[ei[N_EDGES + e]], 1.0f);
}
__global__ void k_dinv(float* __restrict__ deg) {
    int i = blockIdx.x * 256 + threadIdx.x;
    if (i < N_NODES) deg[i] = rsqrtf(fmaxf(deg[i], 1.0f));
}

// ---------------------------------------------------------------- GRU via MFMA
// wave handles 16 nodes. A-frag mapping (self-consistent A/B): row=lane&15,
// k = ks*32 + 8*(lane>>4) + i. C/D (m89): col=lane&15, row=(lane>>4)*4+reg.
__global__ __launch_bounds__(256) void k_gru_mfma(
    const float* __restrict__ x,
    const int*   __restrict__ xtext,
    const float* __restrict__ embed,
    const float* __restrict__ w_ih, const float* __restrict__ w_hh,
    const float* __restrict__ b_ih, const float* __restrict__ b_hh,
    float* __restrict__ hcat)
{
    __shared__ short bfrag[2 * 2 * 12 * 64 * 8];   // [mat][ks][ct][lane][8] = 48KB
    __shared__ short hbuf[4][16 * 64];             // per-wave h transpose, 8KB

    const int tid = threadIdx.x;
    // pack B-fragments: B[k][c] = W[c*64+k]
    for (int u = tid; u < 3072; u += 256) {
        int l   = u & 63;
        int ct  = (u >> 6) % 12;
        int ks  = (u / 768) & 1;
        int mat = u / 1536;
        const float* W = mat ? w_hh : w_ih;
        int c  = ct * 16 + (l & 15);
        int kb = ks * 32 + ((l >> 4) << 3);
        short* dst = &bfrag[u * 8];
        #pragma unroll
        for (int i = 0; i < 8; ++i) dst[i] = f2bf(W[c * 64 + kb + i]);
    }
    __syncthreads();

    const int lane = tid & 63;
    const int wave = tid >> 6;
    const int lg = lane >> 4;    // k-group 0..3
    const int ll = lane & 15;    // row (A) / col (B,C)

    float bi[12], bh[12];
    #pragma unroll
    for (int ct = 0; ct < 12; ++ct) {
        int c = ct * 16 + ll;
        bi[ct] = b_ih[c];
        bh[ct] = b_hh[c];
    }

    const bf16x8* BIH = (const bf16x8*)&bfrag[0];
    const bf16x8* BHH = (const bf16x8*)&bfrag[12288];
    short* hl = &hbuf[wave][0];

    for (int tile = blockIdx.x * 4 + wave; tile < N_NODES / 16; tile += gridDim.x * 4) {
        const int nbase = tile * 16;
        const int nrow  = nbase + ll;

        float h_reg[4][4];
        #pragma unroll
        for (int ct = 0; ct < 4; ++ct)
            #pragma unroll
            for (int q = 0; q < 4; ++q) h_reg[ct][q] = 0.0f;

        // load e(t=0)
        float enf[16];
        {
            int tok = xtext[nrow * 16 + 0];
            const float4* p0 = (const float4*)&embed[tok * 64 + 8 * lg];
            const float4* p1 = (const float4*)&embed[tok * 64 + 32 + 8 * lg];
            float4 a = p0[0], b = p0[1], c = p1[0], d = p1[1];
            enf[0]=a.x; enf[1]=a.y; enf[2]=a.z; enf[3]=a.w;
            enf[4]=b.x; enf[5]=b.y; enf[6]=b.z; enf[7]=b.w;
            enf[8]=c.x; enf[9]=c.y; enf[10]=c.z; enf[11]=c.w;
            enf[12]=d.x; enf[13]=d.y; enf[14]=d.z; enf[15]=d.w;
        }
        bf16x8 eA0, eA1;
        #pragma unroll
        for (int i = 0; i < 8; ++i) { eA0[i] = f2bf(enf[i]); eA1[i] = f2bf(enf[8 + i]); }

        for (int t = 0; t < 16; ++t) {
            // init accumulators with biases
            f32x4 arz[8], ani[4], anh[4];
            #pragma unroll
            for (int ct = 0; ct < 8; ++ct) {
                float v = bi[ct] + bh[ct];
                arz[ct] = (f32x4){v, v, v, v};
            }
            #pragma unroll
            for (int j = 0; j < 4; ++j) {
                float vi = bi[8 + j], vh = bh[8 + j];
                ani[j] = (f32x4){vi, vi, vi, vi};
                anh[j] = (f32x4){vh, vh, vh, vh};
            }

            // issue next-step embedding loads early (hide under MFMAs)
            float enn[16];
            if (t < 15) {
                int tok = xtext[nrow * 16 + t + 1];
                const float4* p0 = (const float4*)&embed[tok * 64 + 8 * lg];
                const float4* p1 = (const float4*)&embed[tok * 64 + 32 + 8 * lg];
                float4 a = p0[0], b = p0[1], c = p1[0], d = p1[1];
                enn[0]=a.x; enn[1]=a.y; enn[2]=a.z; enn[3]=a.w;
                enn[4]=b.x; enn[5]=b.y; enn[6]=b.z; enn[7]=b.w;
                enn[8]=c.x; enn[9]=c.y; enn[10]=c.z; enn[11]=c.w;
                enn[12]=d.x; enn[13]=d.y; enn[14]=d.z; enn[15]=d.w;
            }

            // Gi
            #pragma unroll
            for (int ct = 0; ct < 8; ++ct) {
                arz[ct] = mfma16(eA0, BIH[ct * 64 + lane], arz[ct]);
                arz[ct] = mfma16(eA1, BIH[(12 + ct) * 64 + lane], arz[ct]);
            }
            #pragma unroll
            for (int j = 0; j < 4; ++j) {
                ani[j] = mfma16(eA0, BIH[(8 + j) * 64 + lane], ani[j]);
                ani[j] = mfma16(eA1, BIH[(20 + j) * 64 + lane], ani[j]);
            }

            // Gh (h==0 at t=0; biases already in)
            if (t > 0) {
                #pragma unroll
                for (int ks = 0; ks < 2; ++ks) {
                    int soct = (ks * 4 + lg) ^ (ll & 7);
                    bf16x8 hA = *(const bf16x8*)&hl[ll * 64 + soct * 8];
                    #pragma unroll
                    for (int ct = 0; ct < 8; ++ct)
                        arz[ct] = mfma16(hA, BHH[(ks * 12 + ct) * 64 + lane], arz[ct]);
                    #pragma unroll
                    for (int j = 0; j < 4; ++j)
                        anh[j] = mfma16(hA, BHH[(ks * 12 + 8 + j) * 64 + lane], anh[j]);
                }
            }

            // gates + write transposed h (bf16, XOR-swizzled 16B octs)
            #pragma unroll
            for (int ct = 0; ct < 4; ++ct) {
                #pragma unroll
                for (int q = 0; q < 4; ++q) {
                    float r  = fsig(arz[ct][q]);
                    float z  = fsig(arz[ct + 4][q]);
                    float nn = ftanh(ani[ct][q] + r * anh[ct][q]);
                    float hn = (1.0f - z) * nn + z * h_reg[ct][q];
                    h_reg[ct][q] = hn;
                    int row = 4 * lg + q;
                    int d   = ct * 16 + ll;
                    int soct = (d >> 3) ^ (row & 7);
                    hl[row * 64 + soct * 8 + (d & 7)] = f2bf(hn);
                }
            }

            if (t < 15) {
                #pragma unroll
                for (int i = 0; i < 8; ++i) { eA0[i] = f2bf(enn[i]); eA1[i] = f2bf(enn[8 + i]); }
            }
        }

        // store hcat = [x | h]
        #pragma unroll
        for (int ct = 0; ct < 4; ++ct)
            #pragma unroll
            for (int q = 0; q < 4; ++q)
                hcat[(nbase + 4 * lg + q) * 72 + 8 + ct * 16 + ll] = h_reg[ct][q];
        #pragma unroll
        for (int rep = 0; rep < 2; ++rep) {
            int idx = rep * 64 + lane;
            int nn2 = idx >> 3, f = idx & 7;
            hcat[(nbase + nn2) * 72 + f] = x[(nbase + nn2) * 8 + f];
        }
    }
}

// ---------------------------------------------------------------- dense m = X @ W  (K in {72,64})
template <int K>
__global__ void k_mm(const float* __restrict__ X, const float* __restrict__ W,
                     float* __restrict__ M) {
    __shared__ float Wl[K * 64];
    int tid = threadIdx.x;
    for (int i = tid; i < K * 64; i += 256) Wl[i] = W[i];
    __syncthreads();
    int j = tid & 63;
    int n = blockIdx.x * 4 + (tid >> 6);
    if (n >= N_NODES) return;
    const float* xr = X + n * K;
    float acc = 0.0f;
    #pragma unroll
    for (int k = 0; k < K; ++k) acc += xr[k] * Wl[k * 64 + j];
    M[n * 64 + j] = acc;
}

// ---------------------------------------------------------------- scatter
__global__ void k_scatter(const int* __restrict__ ei, const float* __restrict__ m,
                          const float* __restrict__ dinv, float* __restrict__ acc) {
    int e = blockIdx.x * 4 + (threadIdx.x >> 6);
    if (e >= N_EDGES) return;
    int j = threadIdx.x & 63;
    int r = ei[e], c = ei[N_EDGES + e];
    float nrm = dinv[r] * dinv[c];
    atomicAdd(&acc[c * 64 + j], nrm * m[r * 64 + j]);
}

// ---------------------------------------------------------------- combine
__global__ void k_combine(const float* __restrict__ acc, const float* __restrict__ m,
                          const float* __restrict__ dinv, const float* __restrict__ b,
                          float* __restrict__ out) {
    int i = blockIdx.x * 256 + threadIdx.x;
    if (i >= N_NODES * 64) return;
    int n = i >> 6, j = i & 63;
    float d = dinv[n];
    float v = acc[i] + d * d * m[i] + b[j];
    out[i] = fmaxf(v, 0.0f);
}

// ---------------------------------------------------------------- edge classifier via MFMA
// wave handles 16 edges; A row=edge (lane&15), k = ks*32+8*(lane>>4)+i over
// [h_src | h_dst]; B = Wl1 fragments in VGPRs.
__global__ __launch_bounds__(256) void k_edge_mfma(
    const int* __restrict__ ei, const float* __restrict__ h,
    const float* __restrict__ Wl1, const float* __restrict__ bl1,
    const float* __restrict__ Wf,  const float* __restrict__ bf,
    float* __restrict__ out)
{
    __shared__ float wl_s[128 * 64];   // 32KB stage
    const int tid = threadIdx.x;
    for (int i = tid; i < 128 * 64; i += 256) wl_s[i] = Wl1[i];
    __syncthreads();

    const int lane = tid & 63;
    const int wave = tid >> 6;
    const int lg = lane >> 4;
    const int ll = lane & 15;

    bf16x8 B[16];
    #pragma unroll
    for (int ks = 0; ks < 4; ++ks) {
        #pragma unroll
        for (int ct = 0; ct < 4; ++ct) {
            int c  = ct * 16 + ll;
            int kb = ks * 32 + 8 * lg;
            bf16x8 v;
            #pragma unroll
            for (int i = 0; i < 8; ++i) v[i] = f2bf(wl_s[(kb + i) * 64 + c]);
            B[ks * 4 + ct] = v;
        }
    }
    float wf0[4], wf1[4], bl[4];
    #pragma unroll
    for (int ct = 0; ct < 4; ++ct) {
        int c = ct * 16 + ll;
        wf0[ct] = Wf[c * 2 + 0];
        wf1[ct] = Wf[c * 2 + 1];
        bl[ct]  = bl1[c];
    }
    const float bf0 = bf[0], bf1 = bf[1];

    for (int tile = blockIdx.x * 4 + wave; tile < N_EDGES / 16; tile += gridDim.x * 4) {
        const int ebase = tile * 16;
        const int erow  = ebase + ll;
        const int src = ei[erow];
        const int dst = ei[N_EDGES + erow];

        f32x4 acc[4];
        #pragma unroll
        for (int ct = 0; ct < 4; ++ct) acc[ct] = (f32x4){bl[ct], bl[ct], bl[ct], bl[ct]};

        #pragma unroll
        for (int ks = 0; ks < 4; ++ks) {
            const int node = (ks < 2) ? src : dst;
            const float4* p = (const float4*)&h[node * 64 + (ks & 1) * 32 + 8 * lg];
            float4 a4 = p[0], b4 = p[1];
            float fa[8] = {a4.x, a4.y, a4.z, a4.w, b4.x, b4.y, b4.z, b4.w};
            bf16x8 A;
            #pragma unroll
            for (int i = 0; i < 8; ++i) A[i] = f2bf(fa[i]);
            #pragma unroll
            for (int ct = 0; ct < 4; ++ct) acc[ct] = mfma16(A, B[ks * 4 + ct], acc[ct]);
        }

        // relu + Wf partials, reduce over the 16 cols held by ll
        float p0[4], p1[4];
        #pragma unroll
        for (int q = 0; q < 4; ++q) { p0[q] = 0.0f; p1[q] = 0.0f; }
        #pragma unroll
        for (int ct = 0; ct < 4; ++ct) {
            #pragma unroll
            for (int q = 0; q < 4; ++q) {
                float hd = fmaxf(acc[ct][q], 0.0f);
                p0[q] += hd * wf0[ct];
                p1[q] += hd * wf1[ct];
            }
        }
        #pragma unroll
        for (int m = 1; m <= 8; m <<= 1) {
            #pragma unroll
            for (int q = 0; q < 4; ++q) {
                p0[q] += __shfl_xor(p0[q], m, 64);
                p1[q] += __shfl_xor(p1[q], m, 64);
            }
        }
        if (ll < 8) {
            int q = ll >> 1, cls = ll & 1;
            float l0 = p0[q] + bf0, l1 = p1[q] + bf1;
            float mx  = fmaxf(l0, l1);
            float lse = mx + __logf(__expf(l0 - mx) + __expf(l1 - mx));
            float val = (cls ? l1 : l0) - lse;
            out[(ebase + 4 * lg + q) * 2 + cls] = val;
        }
    }
}

// ---------------------------------------------------------------- launch
extern "C" void kernel_launch(void* const* d_in, const int* in_sizes, int n_in,
                              void* d_out, int out_size, void* d_ws, size_t ws_size,
                              hipStream_t stream) {
    const float* x     = (const float*)d_in[0];
    const int*   ei    = (const int*)  d_in[1];
    const int*   xtext = (const int*)  d_in[2];
    const float* embed = (const float*)d_in[3];
    const float* w_ih  = (const float*)d_in[4];
    const float* w_hh  = (const float*)d_in[5];
    const float* b_ih  = (const float*)d_in[6];
    const float* b_hh  = (const float*)d_in[7];
    const float* W1    = (const float*)d_in[8];
    const float* b1    = (const float*)d_in[9];
    const float* W2    = (const float*)d_in[10];
    const float* b2    = (const float*)d_in[11];
    const float* Wl1   = (const float*)d_in[12];
    const float* bl1   = (const float*)d_in[13];
    const float* Wf    = (const float*)d_in[14];
    const float* bf    = (const float*)d_in[15];
    float* out = (float*)d_out;

    char* ws = (char*)d_ws;
    size_t off = 0;
    auto alloc = [&](size_t bytes) { char* p = ws + off; off += (bytes + 255) & ~size_t(255); return p; };
    float* hcat = (float*)alloc(N_NODES * 72 * 4);
    float* mbuf = (float*)alloc(N_NODES * 64 * 4);
    float* accb = (float*)alloc(N_NODES * 64 * 4);
    float* h1   = (float*)alloc(N_NODES * 64 * 4);
    float* h2   = (float*)alloc(N_NODES * 64 * 4);
    float* dinv = (float*)alloc(N_NODES * 4);

    k_init_deg<<<(N_NODES + 255) / 256, 256, 0, stream>>>(dinv);
    k_deg<<<(N_EDGES + 255) / 256, 256, 0, stream>>>(ei, dinv);
    k_dinv<<<(N_NODES + 255) / 256, 256, 0, stream>>>(dinv);

    k_gru_mfma<<<512, 256, 0, stream>>>(x, xtext, embed, w_ih, w_hh, b_ih, b_hh, hcat);

    k_mm<72><<<(N_NODES + 3) / 4, 256, 0, stream>>>(hcat, W1, mbuf);
    hipMemsetAsync(accb, 0, N_NODES * 64 * 4, stream);
    k_scatter<<<(N_EDGES + 3) / 4, 256, 0, stream>>>(ei, mbuf, dinv, accb);
    k_combine<<<(N_NODES * 64 + 255) / 256, 256, 0, stream>>>(accb, mbuf, dinv, b1, h1);

    k_mm<64><<<(N_NODES + 3) / 4, 256, 0, stream>>>(h1, W2, mbuf);
    hipMemsetAsync(accb, 0, N_NODES * 64 * 4, stream);
    k_scatter<<<(N_EDGES + 3) / 4, 256, 0, stream>>>(ei, mbuf, dinv, accb);
    k_combine<<<(N_NODES * 64 + 255) / 256, 256, 0, stream>>>(accb, mbuf, dinv, b2, h2);

    k_edge_mfma<<<2048, 256, 0, stream>>>(ei, h2, Wl1, bl1, Wf, bf, out);
}

// Round 4
// 428.965 us; speedup vs baseline: 10.3083x; 1.6584x over previous
//
#include <hip/hip_runtime.h>
#include <math.h>

#define N_NODES 50000
#define N_EDGES 800000
#define SCAN_NB ((N_NODES + 255) / 256)   // 196

typedef __attribute__((ext_vector_type(8))) short bf16x8;
typedef __attribute__((ext_vector_type(4))) float f32x4;

__device__ inline short f2bf(float f) {
    union { float f; unsigned u; } v; v.f = f;
    unsigned r = v.u + 0x7FFFu + ((v.u >> 16) & 1u);   // RNE
    return (short)(r >> 16);
}

__device__ inline float fsig(float x)  { return __builtin_amdgcn_rcpf(1.0f + __expf(-x)); }
__device__ inline float ftanh(float x) { float t = __expf(2.0f * x); return 1.0f - 2.0f * __builtin_amdgcn_rcpf(t + 1.0f); }

__device__ inline f32x4 mfma16(bf16x8 a, bf16x8 b, f32x4 c) {
    return __builtin_amdgcn_mfma_f32_16x16x32_bf16(a, b, c, 0, 0, 0);
}

// ================================================================ CSR build
__global__ void k_count(const int* __restrict__ ei, int* __restrict__ cnt) {
    int e = blockIdx.x * 256 + threadIdx.x;
    if (e < N_EDGES) atomicAdd(&cnt[ei[N_EDGES + e]], 1);
}

// block-local inclusive scan; writes block-local EXCLUSIVE scan + block total
__global__ void k_scan_local(const int* __restrict__ cnt, int* __restrict__ excl,
                             int* __restrict__ bsum) {
    __shared__ int s[256];
    int tid = threadIdx.x;
    int i = blockIdx.x * 256 + tid;
    int v = (i < N_NODES) ? cnt[i] : 0;
    s[tid] = v;
    __syncthreads();
    #pragma unroll
    for (int off = 1; off < 256; off <<= 1) {
        int t = (tid >= off) ? s[tid - off] : 0;
        __syncthreads();
        s[tid] += t;
        __syncthreads();
    }
    if (i < N_NODES) excl[i] = s[tid] - v;
    if (tid == 255) bsum[blockIdx.x] = s[255];
}

// single block: exclusive scan of the SCAN_NB block sums, in place
__global__ void k_scan_bsum(int* __restrict__ bsum) {
    __shared__ int s[256];
    int tid = threadIdx.x;
    int v = (tid < SCAN_NB) ? bsum[tid] : 0;
    s[tid] = v;
    __syncthreads();
    #pragma unroll
    for (int off = 1; off < 256; off <<= 1) {
        int t = (tid >= off) ? s[tid - off] : 0;
        __syncthreads();
        s[tid] += t;
        __syncthreads();
    }
    if (tid < SCAN_NB) bsum[tid] = s[tid] - v;
}

// starts/cursor = global exclusive scan; dinv = rsqrt(deg+1)
__global__ void k_make_starts(const int* __restrict__ excl, const int* __restrict__ bsum,
                              const int* __restrict__ cnt,
                              int* __restrict__ starts, int* __restrict__ cursor,
                              float* __restrict__ dinv) {
    int i = blockIdx.x * 256 + threadIdx.x;
    if (i >= N_NODES) return;
    int st = excl[i] + bsum[blockIdx.x];
    starts[i] = st;
    cursor[i] = st;
    dinv[i] = rsqrtf((float)cnt[i] + 1.0f);
}

__global__ void k_fill(const int* __restrict__ ei, int* __restrict__ cursor,
                       int* __restrict__ csr_src) {
    int e = blockIdx.x * 256 + threadIdx.x;
    if (e >= N_EDGES) return;
    int c = ei[N_EDGES + e];
    int p = atomicAdd(&cursor[c], 1);
    csr_src[p] = ei[e];
}

// ================================================================ GRU via MFMA
__global__ __launch_bounds__(256) void k_gru_mfma(
    const float* __restrict__ x,
    const int*   __restrict__ xtext,
    const float* __restrict__ embed,
    const float* __restrict__ w_ih, const float* __restrict__ w_hh,
    const float* __restrict__ b_ih, const float* __restrict__ b_hh,
    float* __restrict__ hcat)
{
    __shared__ short bfrag[2 * 2 * 12 * 64 * 8];   // 48KB
    __shared__ short hbuf[4][16 * 64];             // 8KB

    const int tid = threadIdx.x;
    for (int u = tid; u < 3072; u += 256) {
        int l   = u & 63;
        int ct  = (u >> 6) % 12;
        int ks  = (u / 768) & 1;
        int mat = u / 1536;
        const float* W = mat ? w_hh : w_ih;
        int c  = ct * 16 + (l & 15);
        int kb = ks * 32 + ((l >> 4) << 3);
        short* dst = &bfrag[u * 8];
        #pragma unroll
        for (int i = 0; i < 8; ++i) dst[i] = f2bf(W[c * 64 + kb + i]);
    }
    __syncthreads();

    const int lane = tid & 63;
    const int wave = tid >> 6;
    const int lg = lane >> 4;
    const int ll = lane & 15;

    float bi[12], bh[12];
    #pragma unroll
    for (int ct = 0; ct < 12; ++ct) {
        int c = ct * 16 + ll;
        bi[ct] = b_ih[c];
        bh[ct] = b_hh[c];
    }

    const bf16x8* BIH = (const bf16x8*)&bfrag[0];
    const bf16x8* BHH = (const bf16x8*)&bfrag[12288];
    short* hl = &hbuf[wave][0];

    for (int tile = blockIdx.x * 4 + wave; tile < N_NODES / 16; tile += gridDim.x * 4) {
        const int nbase = tile * 16;
        const int nrow  = nbase + ll;

        float h_reg[4][4];
        #pragma unroll
        for (int ct = 0; ct < 4; ++ct)
            #pragma unroll
            for (int q = 0; q < 4; ++q) h_reg[ct][q] = 0.0f;

        float enf[16];
        {
            int tok = xtext[nrow * 16 + 0];
            const float4* p0 = (const float4*)&embed[tok * 64 + 8 * lg];
            const float4* p1 = (const float4*)&embed[tok * 64 + 32 + 8 * lg];
            float4 a = p0[0], b = p0[1], c = p1[0], d = p1[1];
            enf[0]=a.x; enf[1]=a.y; enf[2]=a.z; enf[3]=a.w;
            enf[4]=b.x; enf[5]=b.y; enf[6]=b.z; enf[7]=b.w;
            enf[8]=c.x; enf[9]=c.y; enf[10]=c.z; enf[11]=c.w;
            enf[12]=d.x; enf[13]=d.y; enf[14]=d.z; enf[15]=d.w;
        }
        bf16x8 eA0, eA1;
        #pragma unroll
        for (int i = 0; i < 8; ++i) { eA0[i] = f2bf(enf[i]); eA1[i] = f2bf(enf[8 + i]); }

        for (int t = 0; t < 16; ++t) {
            f32x4 arz[8], ani[4], anh[4];
            #pragma unroll
            for (int ct = 0; ct < 8; ++ct) {
                float v = bi[ct] + bh[ct];
                arz[ct] = (f32x4){v, v, v, v};
            }
            #pragma unroll
            for (int j = 0; j < 4; ++j) {
                float vi = bi[8 + j], vh = bh[8 + j];
                ani[j] = (f32x4){vi, vi, vi, vi};
                anh[j] = (f32x4){vh, vh, vh, vh};
            }

            float enn[16];
            if (t < 15) {
                int tok = xtext[nrow * 16 + t + 1];
                const float4* p0 = (const float4*)&embed[tok * 64 + 8 * lg];
                const float4* p1 = (const float4*)&embed[tok * 64 + 32 + 8 * lg];
                float4 a = p0[0], b = p0[1], c = p1[0], d = p1[1];
                enn[0]=a.x; enn[1]=a.y; enn[2]=a.z; enn[3]=a.w;
                enn[4]=b.x; enn[5]=b.y; enn[6]=b.z; enn[7]=b.w;
                enn[8]=c.x; enn[9]=c.y; enn[10]=c.z; enn[11]=c.w;
                enn[12]=d.x; enn[13]=d.y; enn[14]=d.z; enn[15]=d.w;
            }

            #pragma unroll
            for (int ct = 0; ct < 8; ++ct) {
                arz[ct] = mfma16(eA0, BIH[ct * 64 + lane], arz[ct]);
                arz[ct] = mfma16(eA1, BIH[(12 + ct) * 64 + lane], arz[ct]);
            }
            #pragma unroll
            for (int j = 0; j < 4; ++j) {
                ani[j] = mfma16(eA0, BIH[(8 + j) * 64 + lane], ani[j]);
                ani[j] = mfma16(eA1, BIH[(20 + j) * 64 + lane], ani[j]);
            }

            if (t > 0) {
                #pragma unroll
                for (int ks = 0; ks < 2; ++ks) {
                    int soct = (ks * 4 + lg) ^ (ll & 7);
                    bf16x8 hA = *(const bf16x8*)&hl[ll * 64 + soct * 8];
                    #pragma unroll
                    for (int ct = 0; ct < 8; ++ct)
                        arz[ct] = mfma16(hA, BHH[(ks * 12 + ct) * 64 + lane], arz[ct]);
                    #pragma unroll
                    for (int j = 0; j < 4; ++j)
                        anh[j] = mfma16(hA, BHH[(ks * 12 + 8 + j) * 64 + lane], anh[j]);
                }
            }

            #pragma unroll
            for (int ct = 0; ct < 4; ++ct) {
                #pragma unroll
                for (int q = 0; q < 4; ++q) {
                    float r  = fsig(arz[ct][q]);
                    float z  = fsig(arz[ct + 4][q]);
                    float nn = ftanh(ani[ct][q] + r * anh[ct][q]);
                    float hn = (1.0f - z) * nn + z * h_reg[ct][q];
                    h_reg[ct][q] = hn;
                    int row = 4 * lg + q;
                    int d   = ct * 16 + ll;
                    int soct = (d >> 3) ^ (row & 7);
                    hl[row * 64 + soct * 8 + (d & 7)] = f2bf(hn);
                }
            }

            if (t < 15) {
                #pragma unroll
                for (int i = 0; i < 8; ++i) { eA0[i] = f2bf(enn[i]); eA1[i] = f2bf(enn[8 + i]); }
            }
        }

        #pragma unroll
        for (int ct = 0; ct < 4; ++ct)
            #pragma unroll
            for (int q = 0; q < 4; ++q)
                hcat[(nbase + 4 * lg + q) * 72 + 8 + ct * 16 + ll] = h_reg[ct][q];
        #pragma unroll
        for (int rep = 0; rep < 2; ++rep) {
            int idx = rep * 64 + lane;
            int nn2 = idx >> 3, f = idx & 7;
            hcat[(nbase + nn2) * 72 + f] = x[(nbase + nn2) * 8 + f];
        }
    }
}

// ================================================================ dense ms = dinv*(X @ W)
template <int K>
__global__ void k_mm(const float* __restrict__ X, const float* __restrict__ W,
                     const float* __restrict__ dinv, float* __restrict__ M) {
    __shared__ float Wl[K * 64];
    int tid = threadIdx.x;
    for (int i = tid; i < K * 64; i += 256) Wl[i] = W[i];
    __syncthreads();
    int j = tid & 63;
    int n = blockIdx.x * 4 + (tid >> 6);
    if (n >= N_NODES) return;
    const float* xr = X + n * K;
    float acc = 0.0f;
    #pragma unroll
    for (int k = 0; k < K; ++k) acc += xr[k] * Wl[k * 64 + j];
    M[n * 64 + j] = dinv[n] * acc;
}

// ================================================================ gather + self + bias + relu
// out[c,j] = relu(dinv[c]*(ms[c,j] + sum_{r in in(c)} ms[r,j]) + b[j])
__global__ __launch_bounds__(256) void k_gather(
    const float* __restrict__ ms, const int* __restrict__ csr_src,
    const int* __restrict__ starts, const int* __restrict__ cnt,
    const float* __restrict__ dinv, const float* __restrict__ b,
    float* __restrict__ out)
{
    int n = blockIdx.x * 4 + (threadIdx.x >> 6);
    if (n >= N_NODES) return;
    int j = threadIdx.x & 63;
    int c = cnt[n];
    const int* lst = csr_src + starts[n];
    float acc = ms[n * 64 + j];   // self-loop term
    int k = 0;
    for (; k + 8 <= c; k += 8) {
        int r[8];
        #pragma unroll
        for (int u = 0; u < 8; ++u) r[u] = lst[k + u];
        #pragma unroll
        for (int u = 0; u < 8; ++u) acc += ms[r[u] * 64 + j];
    }
    for (; k < c; ++k) acc += ms[lst[k] * 64 + j];
    float v = dinv[n] * acc + b[j];
    out[n * 64 + j] = fmaxf(v, 0.0f);
}

// ================================================================ edge classifier via MFMA
__global__ __launch_bounds__(256) void k_edge_mfma(
    const int* __restrict__ ei, const float* __restrict__ h,
    const float* __restrict__ Wl1, const float* __restrict__ bl1,
    const float* __restrict__ Wf,  const float* __restrict__ bf,
    float* __restrict__ out)
{
    __shared__ float wl_s[128 * 64];
    const int tid = threadIdx.x;
    for (int i = tid; i < 128 * 64; i += 256) wl_s[i] = Wl1[i];
    __syncthreads();

    const int lane = tid & 63;
    const int wave = tid >> 6;
    const int lg = lane >> 4;
    const int ll = lane & 15;

    bf16x8 B[16];
    #pragma unroll
    for (int ks = 0; ks < 4; ++ks) {
        #pragma unroll
        for (int ct = 0; ct < 4; ++ct) {
            int c  = ct * 16 + ll;
            int kb = ks * 32 + 8 * lg;
            bf16x8 v;
            #pragma unroll
            for (int i = 0; i < 8; ++i) v[i] = f2bf(wl_s[(kb + i) * 64 + c]);
            B[ks * 4 + ct] = v;
        }
    }
    float wf0[4], wf1[4], bl[4];
    #pragma unroll
    for (int ct = 0; ct < 4; ++ct) {
        int c = ct * 16 + ll;
        wf0[ct] = Wf[c * 2 + 0];
        wf1[ct] = Wf[c * 2 + 1];
        bl[ct]  = bl1[c];
    }
    const float bf0 = bf[0], bf1 = bf[1];

    for (int tile = blockIdx.x * 4 + wave; tile < N_EDGES / 16; tile += gridDim.x * 4) {
        const int ebase = tile * 16;
        const int erow  = ebase + ll;
        const int src = ei[erow];
        const int dst = ei[N_EDGES + erow];

        f32x4 acc[4];
        #pragma unroll
        for (int ct = 0; ct < 4; ++ct) acc[ct] = (f32x4){bl[ct], bl[ct], bl[ct], bl[ct]};

        #pragma unroll
        for (int ks = 0; ks < 4; ++ks) {
            const int node = (ks < 2) ? src : dst;
            const float4* p = (const float4*)&h[node * 64 + (ks & 1) * 32 + 8 * lg];
            float4 a4 = p[0], b4 = p[1];
            float fa[8] = {a4.x, a4.y, a4.z, a4.w, b4.x, b4.y, b4.z, b4.w};
            bf16x8 A;
            #pragma unroll
            for (int i = 0; i < 8; ++i) A[i] = f2bf(fa[i]);
            #pragma unroll
            for (int ct = 0; ct < 4; ++ct) acc[ct] = mfma16(A, B[ks * 4 + ct], acc[ct]);
        }

        float p0[4], p1[4];
        #pragma unroll
        for (int q = 0; q < 4; ++q) { p0[q] = 0.0f; p1[q] = 0.0f; }
        #pragma unroll
        for (int ct = 0; ct < 4; ++ct) {
            #pragma unroll
            for (int q = 0; q < 4; ++q) {
                float hd = fmaxf(acc[ct][q], 0.0f);
                p0[q] += hd * wf0[ct];
                p1[q] += hd * wf1[ct];
            }
        }
        #pragma unroll
        for (int m = 1; m <= 8; m <<= 1) {
            #pragma unroll
            for (int q = 0; q < 4; ++q) {
                p0[q] += __shfl_xor(p0[q], m, 64);
                p1[q] += __shfl_xor(p1[q], m, 64);
            }
        }
        if (ll < 8) {
            int q = ll >> 1, cls = ll & 1;
            float l0 = p0[q] + bf0, l1 = p1[q] + bf1;
            float mx  = fmaxf(l0, l1);
            float lse = mx + __logf(__expf(l0 - mx) + __expf(l1 - mx));
            float val = (cls ? l1 : l0) - lse;
            out[(ebase + 4 * lg + q) * 2 + cls] = val;
        }
    }
}

// ================================================================ launch
extern "C" void kernel_launch(void* const* d_in, const int* in_sizes, int n_in,
                              void* d_out, int out_size, void* d_ws, size_t ws_size,
                              hipStream_t stream) {
    const float* x     = (const float*)d_in[0];
    const int*   ei    = (const int*)  d_in[1];
    const int*   xtext = (const int*)  d_in[2];
    const float* embed = (const float*)d_in[3];
    const float* w_ih  = (const float*)d_in[4];
    const float* w_hh  = (const float*)d_in[5];
    const float* b_ih  = (const float*)d_in[6];
    const float* b_hh  = (const float*)d_in[7];
    const float* W1    = (const float*)d_in[8];
    const float* b1    = (const float*)d_in[9];
    const float* W2    = (const float*)d_in[10];
    const float* b2    = (const float*)d_in[11];
    const float* Wl1   = (const float*)d_in[12];
    const float* bl1   = (const float*)d_in[13];
    const float* Wf    = (const float*)d_in[14];
    const float* bf    = (const float*)d_in[15];
    float* out = (float*)d_out;

    char* ws = (char*)d_ws;
    size_t off = 0;
    auto alloc = [&](size_t bytes) { char* p = ws + off; off += (bytes + 255) & ~size_t(255); return p; };
    float* hcat    = (float*)alloc(N_NODES * 72 * 4);
    float* ms      = (float*)alloc(N_NODES * 64 * 4);
    float* h1      = (float*)alloc(N_NODES * 64 * 4);
    float* h2      = (float*)alloc(N_NODES * 64 * 4);
    float* dinv    = (float*)alloc(N_NODES * 4);
    int*   cnt     = (int*)  alloc(N_NODES * 4);
    int*   excl    = (int*)  alloc(N_NODES * 4);
    int*   starts  = (int*)  alloc(N_NODES * 4);
    int*   cursor  = (int*)  alloc(N_NODES * 4);
    int*   bsum    = (int*)  alloc(SCAN_NB * 4);
    int*   csr_src = (int*)  alloc(N_EDGES * 4);

    // ---- CSR build (shared by both GCN layers)
    hipMemsetAsync(cnt, 0, N_NODES * 4, stream);
    k_count<<<(N_EDGES + 255) / 256, 256, 0, stream>>>(ei, cnt);
    k_scan_local<<<SCAN_NB, 256, 0, stream>>>(cnt, excl, bsum);
    k_scan_bsum<<<1, 256, 0, stream>>>(bsum);
    k_make_starts<<<SCAN_NB, 256, 0, stream>>>(excl, bsum, cnt, starts, cursor, dinv);
    k_fill<<<(N_EDGES + 255) / 256, 256, 0, stream>>>(ei, cursor, csr_src);

    // ---- text encoder
    k_gru_mfma<<<512, 256, 0, stream>>>(x, xtext, embed, w_ih, w_hh, b_ih, b_hh, hcat);

    // ---- GCN layer 1
    k_mm<72><<<(N_NODES + 3) / 4, 256, 0, stream>>>(hcat, W1, dinv, ms);
    k_gather<<<(N_NODES + 3) / 4, 256, 0, stream>>>(ms, csr_src, starts, cnt, dinv, b1, h1);

    // ---- GCN layer 2
    k_mm<64><<<(N_NODES + 3) / 4, 256, 0, stream>>>(h1, W2, dinv, ms);
    k_gather<<<(N_NODES + 3) / 4, 256, 0, stream>>>(ms, csr_src, starts, cnt, dinv, b2, h2);

    // ---- edge classifier
    k_edge_mfma<<<2048, 256, 0, stream>>>(ei, h2, Wl1, bl1, Wf, bf, out);
}